// Round 17
// baseline (86.427 us; speedup 1.0000x reference)
//
#include <hip/hip_runtime.h>

// out[b,h,t,f] = sum_{r=0..64} a[b,h,t,r] * v[b,h, t+r-32, f]  (zero-padded in t)
// B=8 H=16 T=4096 F=64 R=65, fp32 in/out. bf16 MFMA (absmax 0.25 vs thr 1.0).
//
// Round 17: BARRIER-FREE, LDS-FREE. Both MFMA operands read directly from
// global:
//   B (v): lane(n,hi) j <- v[tb+16kb+j][32wc+n]      (2x128B segs/instr, L2-hit)
//   A (a): lane(n,hi) j <- a[t0+32wr+n][cp+j-n]      (8 consecutive dwords,
//          per-lane base a+(bh*T+t0+Rw)*65-n, compile-time offsets; provably
//          in-bounds: min addr = 64n >= 0, max = last element exactly)
//   band zeros: av[j]=0 unless (unsigned)(cp+j-n)<=64  (1 cndmask/elem)
// No phases -> every wave is a straight-line stream of 96 independent loads;
// launch_bounds(256,4) = 128-VGPR budget so the scheduler can keep ~24-32
// loads in flight (r11 capped at 8 under the 64-VGPR/8-wave budget).

#define TT 4096
#define RRR 65
#define FF 64

typedef short bf16x8 __attribute__((ext_vector_type(8)));
typedef float f32x16 __attribute__((ext_vector_type(16)));

__device__ __forceinline__ unsigned short f2bf(float x) {
    unsigned int u = __float_as_uint(x);
    u += 0x7fff + ((u >> 16) & 1);            // RNE
    return (unsigned short)(u >> 16);
}
__device__ __forceinline__ unsigned pk2(float lo, float hi) {
    return (unsigned)f2bf(lo) | ((unsigned)f2bf(hi) << 16);
}

__global__ __launch_bounds__(256, 4)
void unfold_mfma(const float* __restrict__ a, const float* __restrict__ v,
                 float* __restrict__ out) {
    const int tid = threadIdx.x;
    const int f   = tid & 63;
    const int wv  = tid >> 6;          // 0..3
    const int n   = f & 31;
    const int hi  = f >> 5;
    const int wr  = wv >> 1;           // row half of the 64-row tile
    const int wc  = wv & 1;            // col half
    const int Rw  = 32 * wr + n;

    // ---- bijective XCD swizzle: each XCD owns 16 whole (b,h) slabs ----
    const int lid = ((blockIdx.x & 7) << 10) | (blockIdx.x >> 3);
    const int bh = lid >> 6;                    // 64 tiles per (b,h)
    const int t0 = (lid & 63) << 6;

    // per-lane A base: a[t0+Rw][.] shifted by -n so offset cp+j is compile-time
    const float* arow = a + (size_t)(bh * TT + t0 + Rw) * RRR - n;
    const float* vp   = v + (size_t)bh * TT * FF + 32 * wc + n;
    const int    tb   = t0 + 32 * wr - 32 + 8 * hi;   // v row for (kb=0, j=0)
    const bool interior = (t0 >= 32) && (t0 + 96 <= TT);   // 62 of 64 tiles

    f32x16 acc = {};
    #pragma unroll
    for (int kb = 0; kb < 6; ++kb) {
        const int cp = kb * 16 + hi * 8;
        float av[8], xv[8];
        #pragma unroll
        for (int j = 0; j < 8; ++j)
            av[j] = arow[cp + j];                     // base + imm offset
        if (interior) {
            #pragma unroll
            for (int j = 0; j < 8; ++j)
                xv[j] = vp[(size_t)(tb + 16 * kb + j) * FF];
        } else {
            #pragma unroll
            for (int j = 0; j < 8; ++j) {
                int t = tb + 16 * kb + j;
                xv[j] = (t >= 0 && t < TT) ? vp[(size_t)t * FF] : 0.f;
            }
        }
        #pragma unroll
        for (int j = 0; j < 8; ++j)                   // band mask: r in [0,64]
            av[j] = ((unsigned)(cp + j - n) <= 64u) ? av[j] : 0.f;

        union { bf16x8 v8; unsigned u[4]; } au, bu;
        au.u[0] = pk2(av[0], av[1]); au.u[1] = pk2(av[2], av[3]);
        au.u[2] = pk2(av[4], av[5]); au.u[3] = pk2(av[6], av[7]);
        bu.u[0] = pk2(xv[0], xv[1]); bu.u[1] = pk2(xv[2], xv[3]);
        bu.u[2] = pk2(xv[4], xv[5]); bu.u[3] = pk2(xv[6], xv[7]);
        acc = __builtin_amdgcn_mfma_f32_32x32x16_bf16(au.v8, bu.v8, acc, 0, 0, 0);
    }

    // ---- store: C/D col = lane&31, row = (reg&3) + 8*(reg>>2) + 4*(lane>>5) ----
    float* op = out + (size_t)bh * TT * FF + (size_t)(t0 + 32 * wr) * FF + 32 * wc;
    #pragma unroll
    for (int reg = 0; reg < 16; ++reg) {
        int row = (reg & 3) + 8 * (reg >> 2) + 4 * hi;
        __builtin_nontemporal_store(acc[reg], &op[row * FF + n]);
    }
}

extern "C" void kernel_launch(void* const* d_in, const int* in_sizes, int n_in,
                              void* d_out, int out_size, void* d_ws, size_t ws_size,
                              hipStream_t stream) {
    const float* a = (const float*)d_in[0];
    const float* v = (const float*)d_in[1];
    float* out = (float*)d_out;

    const int BH = in_sizes[1] / (TT * FF);      // 128
    const int grid = BH * 64;                    // 8192 single-tile blocks

    unfold_mfma<<<grid, 256, 0, stream>>>(a, v, out);
}

// Round 18
// 69.191 us; speedup vs baseline: 1.2491x; 1.2491x over previous
//
#include <hip/hip_runtime.h>

// out[b,h,t,f] = sum_{r=0..64} a[b,h,t,r] * v[b,h, t+r-32, f]  (zero-padded in t)
// B=8 H=16 T=4096 F=64 R=65, fp32 in/out. bf16 MFMA (absmax 0.25 vs thr 1.0).
//
// Round 18: RESTORE the round-14 optimum (69.64us) — r17's barrier-free
// direct-A regressed (256B inter-lane stride -> uncoalesced A, FETCH +40MB).
// Final structure: 512 thr / 8 waves / TILE=128; coalesced a float4 burst ->
// LDS band-densify; B fragments read directly from global v (L2-resident via
// bijective XCD swizzle); lgkmcnt-only barriers; 4B nontemporal stores.
// Ablation history: v-ring(-), ILP pipeline(-, compiler re-sinks), VALU cut(-),
// block doubling(0), 16B-store epilogue(0), barrier-free(-). Traffic at floor
// (FETCH 136MB = a, WRITE 131MB = out), occupancy ~75%, no pipe >25%.
//   OUT(32x64) = Ablk(32x96) x Vslice(96x64), per wave (wr,wc)
//   Ablk[i][c] = (0<=c-i<=64) ? a[t0+32wr+i][c-i] : 0   (band, LDS-densified)
//   B[k][col]: lane(n,hi) elem j <- v[t0+32wr-32+16kb+8hi+j][32wc+n]

#define TT 4096
#define RRR 65
#define FF 64
#define TILE 128
#define SA_S 100     // bf16 row stride: 200B rows -> 2-way (free) on A b128 reads

typedef short bf16x8 __attribute__((ext_vector_type(8)));
typedef float f32x16 __attribute__((ext_vector_type(16)));

__device__ __forceinline__ unsigned short f2bf(float x) {
    unsigned int u = __float_as_uint(x);
    u += 0x7fff + ((u >> 16) & 1);            // RNE
    return (unsigned short)(u >> 16);
}
__device__ __forceinline__ unsigned pk2(float lo, float hi) {
    return (unsigned)f2bf(lo) | ((unsigned)f2bf(hi) << 16);
}

// Barrier with LDS-only drain: global loads/stores stay in flight (no vmcnt).
#define BAR() do {                                                             \
    asm volatile("s_waitcnt lgkmcnt(0)" ::: "memory");                         \
    __builtin_amdgcn_sched_barrier(0);                                         \
    __builtin_amdgcn_s_barrier();                                              \
    __builtin_amdgcn_sched_barrier(0);                                         \
} while (0)

__global__ __launch_bounds__(512, 8)
void unfold_mfma(const float* __restrict__ a, const float* __restrict__ v,
                 float* __restrict__ out) {
    __shared__ __align__(16) unsigned short sa[TILE * SA_S];   // 25600 B

    const int tid = threadIdx.x;
    const int f   = tid & 63;
    const int wv  = tid >> 6;          // 0..7
    const int n   = f & 31;
    const int hi  = f >> 5;
    const int wr  = wv >> 1;           // 0..3: row quadrant
    const int wc  = wv & 1;            // col half
    const int Rw  = 32 * wr + n;       // sa row; Rw&31 == n (band mapping holds)

    // ---- bijective XCD swizzle: 4096 blocks, each XCD owns 512 consecutive
    //      logical blocks = 16 whole (b,h) slabs -> v window L2-resident ----
    const int lid = ((blockIdx.x & 7) << 9) | (blockIdx.x >> 3);
    const int bh = lid >> 5;                    // 32 tiles per (b,h)
    const int t0 = (lid & 31) << 7;

    const float* arow = a + ((size_t)bh * TT + t0) * RRR;
    const float* vsl  = v + (size_t)bh * TT * FF;

    // ---- issue a loads early (latency hides under prefill + barrier) ----
    float4 aq[4];
    #pragma unroll
    for (int it = 0; it < 4; ++it) {
        int lin = tid + it * 512;
        if (lin < TILE * 15) {
            int R = lin / 15, j = lin - R * 15;
            int r0 = (4 - (R & 3)) & 3;
            aq[it] = *(const float4*)(arow + (size_t)R * RRR + r0 + 4 * j);
        }
    }
    float ae[2];
    #pragma unroll
    for (int it = 0; it < 2; ++it) {
        int lin = tid + it * 512;
        if (lin < TILE * 5) {
            int R = lin / 5, e = lin - R * 5;
            int r0 = (4 - (R & 3)) & 3;
            int r = (e < r0) ? e : 60 + e;      // head [0,r0) + tail [r0+60,64]
            ae[it] = arow[(size_t)R * RRR + r];
        }
    }

    // ---- zero-prefill sa (band complement must be 0): 3200 uint4 ----
    {
        uint4 z = make_uint4(0, 0, 0, 0);
        uint4* sp = (uint4*)sa;
        #pragma unroll
        for (int it = 0; it < 4; ++it) {
            int lin = tid + it * 512;
            if (lin < (TILE * SA_S) / 8) sp[lin] = z;
        }
    }
    BAR();

    // ---- scatter a band: sa[R][(R&31) + r] = bf16(a[t0+R][r]) ----
    #pragma unroll
    for (int it = 0; it < 4; ++it) {
        int lin = tid + it * 512;
        if (lin < TILE * 15) {
            int R = lin / 15, j = lin - R * 15;
            int r0 = (4 - (R & 3)) & 3;
            int rq = r0 + 4 * j;
            float4 q = aq[it];
            uint2 pw; pw.x = pk2(q.x, q.y); pw.y = pk2(q.z, q.w);
            *(uint2*)&sa[R * SA_S + (R & 31) + rq] = pw;   // (R&31)+rq ≡ 0 mod 4
        }
    }
    #pragma unroll
    for (int it = 0; it < 2; ++it) {
        int lin = tid + it * 512;
        if (lin < TILE * 5) {
            int R = lin / 5, e = lin - R * 5;
            int r0 = (4 - (R & 3)) & 3;
            int r = (e < r0) ? e : 60 + e;
            sa[R * SA_S + (R & 31) + r] = f2bf(ae[it]);
        }
    }
    BAR();

    // ---- MFMA: B fragments straight from global v (coalesced 2x128B/instr) ----
    const int fcol = 32 * wc + n;
    const int tb   = t0 + 32 * wr - 32 + 8 * hi;   // t for (kb=0, j=0)
    const float* vp = vsl + fcol;

    f32x16 acc = {};
    if (t0 >= 32 && t0 + 192 <= TT) {              // interior: 30 of 32 tiles
        #pragma unroll
        for (int kb = 0; kb < 6; ++kb) {
            float x[8];
            #pragma unroll
            for (int j = 0; j < 8; ++j)
                x[j] = vp[(size_t)(tb + 16 * kb + j) * FF];
            union { bf16x8 v8; unsigned u[4]; } bu;
            bu.u[0] = pk2(x[0], x[1]); bu.u[1] = pk2(x[2], x[3]);
            bu.u[2] = pk2(x[4], x[5]); bu.u[3] = pk2(x[6], x[7]);
            bf16x8 af = *(const bf16x8*)&sa[Rw * SA_S + kb * 16 + hi * 8];
            acc = __builtin_amdgcn_mfma_f32_32x32x16_bf16(af, bu.v8, acc, 0, 0, 0);
        }
    } else {                                       // t-boundary tiles
        #pragma unroll
        for (int kb = 0; kb < 6; ++kb) {
            float x[8];
            #pragma unroll
            for (int j = 0; j < 8; ++j) {
                int t = tb + 16 * kb + j;
                x[j] = (t >= 0 && t < TT) ? vp[(size_t)t * FF] : 0.f;
            }
            union { bf16x8 v8; unsigned u[4]; } bu;
            bu.u[0] = pk2(x[0], x[1]); bu.u[1] = pk2(x[2], x[3]);
            bu.u[2] = pk2(x[4], x[5]); bu.u[3] = pk2(x[6], x[7]);
            bf16x8 af = *(const bf16x8*)&sa[Rw * SA_S + kb * 16 + hi * 8];
            acc = __builtin_amdgcn_mfma_f32_32x32x16_bf16(af, bu.v8, acc, 0, 0, 0);
        }
    }

    // ---- store: C/D col = lane&31, row = (reg&3) + 8*(reg>>2) + 4*(lane>>5) ----
    float* op = out + (size_t)bh * TT * FF + (size_t)(t0 + 32 * wr) * FF + 32 * wc;
    #pragma unroll
    for (int reg = 0; reg < 16; ++reg) {
        int row = (reg & 3) + 8 * (reg >> 2) + 4 * hi;
        __builtin_nontemporal_store(acc[reg], &op[row * FF + n]);
    }
}

extern "C" void kernel_launch(void* const* d_in, const int* in_sizes, int n_in,
                              void* d_out, int out_size, void* d_ws, size_t ws_size,
                              hipStream_t stream) {
    const float* a = (const float*)d_in[0];
    const float* v = (const float*)d_in[1];
    float* out = (float*)d_out;

    const int BH = in_sizes[1] / (TT * FF);      // 128
    const int grid = BH * (TT / TILE);           // 4096 blocks

    unfold_mfma<<<grid, 512, 0, stream>>>(a, v, out);
}